// Round 3
// baseline (768.329 us; speedup 1.0000x reference)
//
#include <hip/hip_runtime.h>

typedef __attribute__((ext_vector_type(8))) short short8;
typedef __attribute__((ext_vector_type(4))) float float4v;

__device__ __forceinline__ unsigned short f2bf(float f) {
    unsigned int u = __float_as_uint(f);
    u += 0x7fffu + ((u >> 16) & 1u);   // round-to-nearest-even
    return (unsigned short)(u >> 16);
}

#define GRID 256
#define MT   32        // atom rows per tile

// Dense multi-expert MoE: each wave owns one expert, that expert's W1 lives in
// 128 VGPRs as bf16 MFMA fragments (loaded once per persistent block).
// desc is streamed sequentially (no sort/gather); epilogue masks by elem[m]==e.
// waves: wv&3 = expert, wv>>2 = 16-row half of the 32-row tile.
__global__ __launch_bounds__(512, 2)
void fused_moe_kernel(const int* __restrict__ elem,
                      const float* __restrict__ desc,
                      const float* __restrict__ W1,
                      const float* __restrict__ b1,
                      const float* __restrict__ W2,
                      const float* __restrict__ b2,
                      float* __restrict__ out, int n) {
    __shared__ unsigned short As[2][MT * 128];   // 2 x 8 KB, XOR-swizzled bf16

    const int ntiles = (n + MT - 1) / MT;
    int tile = blockIdx.x;
    if (tile >= ntiles) return;

    const int t    = threadIdx.x;
    const int wv   = t >> 6;           // 0..7
    const int lane = t & 63;
    const int quad = lane >> 4;        // k-chunk subgroup
    const int l16  = lane & 15;        // B col-n / A row within 16
    const int e    = wv & 3;           // expert
    const int mb   = (wv >> 2) * 16;   // row half
    const int r7   = l16 & 7;

    // ---- persistent B: expert e's W1 -> bf16 fragments in registers ----
    // frag(ks,nt): lane holds W1T[e][n=nt*16+l16][k=(ks*4+quad)*8 + j], j=0..7
    short8 bfr[4][8];
    {
        const float* Wp = W1 + (size_t)e * 16384 + (size_t)(quad * 8) * 128 + l16;
        #pragma unroll
        for (int ks = 0; ks < 4; ++ks) {
            #pragma unroll
            for (int nt = 0; nt < 8; ++nt) {
                const float* p = Wp + (size_t)(ks * 32) * 128 + nt * 16;
                short8 b;
                #pragma unroll
                for (int j = 0; j < 8; ++j) b[j] = (short)f2bf(p[(size_t)j * 128]);
                bfr[ks][nt] = b;
            }
        }
    }
    float b1v[8], w2v[8];
    #pragma unroll
    for (int nt = 0; nt < 8; ++nt) {
        b1v[nt] = b1[e * 128 + nt * 16 + l16];
        w2v[nt] = W2[e * 128 + nt * 16 + l16];
    }
    const float b2e = b2[e];

    // staging geometry: c = 16B fp32 chunk (4 floats), rows r0, r0+1 per thread
    const int c  = t & 31;
    const int r0 = (t >> 5) * 2;

    // prologue: stage first tile into buf 0
    float4 rv[2];
    #pragma unroll
    for (int p = 0; p < 2; ++p) {
        int rg = tile * MT + r0 + p;
        if (rg >= n) rg = n - 1;
        rv[p] = *(const float4*)(desc + (size_t)rg * 128 + c * 4);
    }
    #pragma unroll
    for (int p = 0; p < 2; ++p) {
        const int r = r0 + p;
        ushort4 pk;
        pk.x = f2bf(rv[p].x); pk.y = f2bf(rv[p].y);
        pk.z = f2bf(rv[p].z); pk.w = f2bf(rv[p].w);
        const int pc = (c >> 1) ^ (r & 7);
        *(ushort4*)(&As[0][r * 128 + pc * 8 + (c & 1) * 4]) = pk;
    }
    __syncthreads();

    int buf = 0;
    for (; tile < ntiles; tile += GRID) {
        const int nxt = tile + GRID;
        const bool has_next = (nxt < ntiles);
        if (has_next) {                         // issue-early prefetch (T14)
            #pragma unroll
            for (int p = 0; p < 2; ++p) {
                int rg = nxt * MT + r0 + p;
                if (rg >= n) rg = n - 1;
                rv[p] = *(const float4*)(desc + (size_t)rg * 128 + c * 4);
            }
        }

        // ---- compute this tile from As[buf] ----
        float4v acc[8] = {};
        #pragma unroll
        for (int ks = 0; ks < 4; ++ks) {
            const int pco = ((ks * 4 + quad) ^ r7) * 8;
            const short8 a0 = *(const short8*)(&As[buf][(mb + l16) * 128 + pco]);
            #pragma unroll
            for (int nt = 0; nt < 8; ++nt)
                acc[nt] = __builtin_amdgcn_mfma_f32_16x16x32_bf16(a0, bfr[ks][nt], acc[nt], 0, 0, 0);
        }

        // ---- fused layer 2: y[m] = sum_n relu(h+b1)*w2 + b2, masked write ----
        float y[4] = {0.f, 0.f, 0.f, 0.f};
        #pragma unroll
        for (int nt = 0; nt < 8; ++nt) {
            const float4v v = acc[nt];
            #pragma unroll
            for (int rr = 0; rr < 4; ++rr)
                y[rr] += fmaxf(v[rr] + b1v[nt], 0.f) * w2v[nt];
        }
        #pragma unroll
        for (int off = 1; off < 16; off <<= 1) {
            #pragma unroll
            for (int rr = 0; rr < 4; ++rr) y[rr] += __shfl_xor(y[rr], off, 16);
        }
        if (l16 == 0) {
            #pragma unroll
            for (int rr = 0; rr < 4; ++rr) {
                const int gm = tile * MT + mb + quad * 4 + rr;   // C row = quad*4+reg
                if (gm < n && elem[gm] == e) out[gm] = y[rr] + b2e;
            }
        }

        // ---- write prefetched tile into As[buf^1] ----
        if (has_next) {
            #pragma unroll
            for (int p = 0; p < 2; ++p) {
                const int r = r0 + p;
                ushort4 pk;
                pk.x = f2bf(rv[p].x); pk.y = f2bf(rv[p].y);
                pk.z = f2bf(rv[p].z); pk.w = f2bf(rv[p].w);
                const int pc = (c >> 1) ^ (r & 7);
                *(ushort4*)(&As[buf ^ 1][r * 128 + pc * 8 + (c & 1) * 4]) = pk;
            }
        }
        __syncthreads();
        buf ^= 1;
    }
}

extern "C" void kernel_launch(void* const* d_in, const int* in_sizes, int n_in,
                              void* d_out, int out_size, void* d_ws, size_t ws_size,
                              hipStream_t stream) {
    const int*   elem = (const int*)d_in[0];
    const float* desc = (const float*)d_in[1];
    const float* W1   = (const float*)d_in[2];
    const float* b1   = (const float*)d_in[3];
    const float* W2   = (const float*)d_in[4];
    const float* b2   = (const float*)d_in[5];
    float* out = (float*)d_out;
    const int n = in_sizes[0];
    if (n <= 0) return;

    fused_moe_kernel<<<GRID, 512, 0, stream>>>(elem, desc, W1, b1, W2, b2, out, n);
}